// Round 1
// baseline (355.069 us; speedup 1.0000x reference)
//
#include <hip/hip_runtime.h>

#define MARGIN 0.5f

// x: [V, C, T] fp32, T=128 contiguous. target: [V, C] int.
// Each half-wave (32 lanes) processes CHUNKS of 4 consecutive rows (4 x 512 B),
// issuing 4 independent global_load_dwordx4 per lane per iteration so >=4 loads
// are in flight per wave (plus 8 blocks/CU occupancy) -> HBM-BW-bound, not
// latency-bound. Sum max(0, x - pos + margin) over ALL t, then subtract the
// exact MARGIN contribution of t==target once per row.
__global__ __launch_bounds__(256, 8) void margin_loss_kernel(
    const float* __restrict__ x,
    const int* __restrict__ target,
    float* __restrict__ out,
    int rows,          // V*C
    float inv_cnt)     // 1 / (V*C*(T-1))
{
    const int T = 128;
    const int tid = threadIdx.x;
    const int lane = tid & 63;          // lane in wave (wave64)
    const int wave = tid >> 6;          // wave in block: 0..3
    const int gl = lane & 31;           // lane within half-wave group
    const int group = lane >> 5;        // which half-wave (0/1)

    // half-wave slots across the whole grid
    const int slot = ((blockIdx.x * 4 + wave) << 1) + group;
    const int total_slots = gridDim.x * 8;
    const int stride = total_slots * 4; // rows advanced per iteration (chunks of 4)

    float acc = 0.0f;
    int rows_handled = 0;

    int base = slot * 4;
    for (; base + 4 <= rows; base += stride) {
        // ---- issue all 4 row loads up front (independent, one shared base) ----
        const float4* rowp = (const float4*)(x + (size_t)base * T);
        float4 v0 = rowp[gl];
        float4 v1 = rowp[gl + 32];      // +512 B  (T=128 floats -> 32 float4)
        float4 v2 = rowp[gl + 64];      // +1024 B
        float4 v3 = rowp[gl + 96];      // +1536 B
        int t0 = target[base + 0];
        int t1 = target[base + 1];
        int t2 = target[base + 2];
        int t3 = target[base + 3];

        // ---- consume ----
        {
            float lo = (t0 & 1) ? v0.y : v0.x;
            float hi = (t0 & 1) ? v0.w : v0.z;
            float comp = (t0 & 2) ? hi : lo;
            float pos = __shfl(comp, (group << 5) + (t0 >> 2), 64);
            const float b = MARGIN - pos;
            acc += fmaxf(v0.x + b, 0.0f) + fmaxf(v0.y + b, 0.0f)
                 + fmaxf(v0.z + b, 0.0f) + fmaxf(v0.w + b, 0.0f);
        }
        {
            float lo = (t1 & 1) ? v1.y : v1.x;
            float hi = (t1 & 1) ? v1.w : v1.z;
            float comp = (t1 & 2) ? hi : lo;
            float pos = __shfl(comp, (group << 5) + (t1 >> 2), 64);
            const float b = MARGIN - pos;
            acc += fmaxf(v1.x + b, 0.0f) + fmaxf(v1.y + b, 0.0f)
                 + fmaxf(v1.z + b, 0.0f) + fmaxf(v1.w + b, 0.0f);
        }
        {
            float lo = (t2 & 1) ? v2.y : v2.x;
            float hi = (t2 & 1) ? v2.w : v2.z;
            float comp = (t2 & 2) ? hi : lo;
            float pos = __shfl(comp, (group << 5) + (t2 >> 2), 64);
            const float b = MARGIN - pos;
            acc += fmaxf(v2.x + b, 0.0f) + fmaxf(v2.y + b, 0.0f)
                 + fmaxf(v2.z + b, 0.0f) + fmaxf(v2.w + b, 0.0f);
        }
        {
            float lo = (t3 & 1) ? v3.y : v3.x;
            float hi = (t3 & 1) ? v3.w : v3.z;
            float comp = (t3 & 2) ? hi : lo;
            float pos = __shfl(comp, (group << 5) + (t3 >> 2), 64);
            const float b = MARGIN - pos;
            acc += fmaxf(v3.x + b, 0.0f) + fmaxf(v3.y + b, 0.0f)
                 + fmaxf(v3.z + b, 0.0f) + fmaxf(v3.w + b, 0.0f);
        }
        rows_handled += 4;
    }

    // tail: at most 3 rows (only if rows % 4 != 0; dead for rows=524288)
    for (int row = base; row < rows; ++row) {
        const float4 v = ((const float4*)(x + (size_t)row * T))[gl];
        const int tgt = target[row];
        float lo = (tgt & 1) ? v.y : v.x;
        float hi = (tgt & 1) ? v.w : v.z;
        float comp = (tgt & 2) ? hi : lo;
        float pos = __shfl(comp, (group << 5) + (tgt >> 2), 64);
        const float b = MARGIN - pos;
        acc += fmaxf(v.x + b, 0.0f) + fmaxf(v.y + b, 0.0f)
             + fmaxf(v.z + b, 0.0f) + fmaxf(v.w + b, 0.0f);
        rows_handled++;
    }

    // remove the t==target term: it is exactly MARGIN per row
    if (gl == 0) acc -= MARGIN * (float)rows_handled;

    // wave reduction (64 lanes)
    #pragma unroll
    for (int off = 32; off > 0; off >>= 1)
        acc += __shfl_down(acc, off, 64);

    __shared__ float s[4];
    if (lane == 0) s[wave] = acc;
    __syncthreads();
    if (tid == 0) {
        float total = (s[0] + s[1]) + (s[2] + s[3]);
        atomicAdd(out, total * inv_cnt);
    }
}

extern "C" void kernel_launch(void* const* d_in, const int* in_sizes, int n_in,
                              void* d_out, int out_size, void* d_ws, size_t ws_size,
                              hipStream_t stream) {
    const float* x = (const float*)d_in[0];
    const int* target = (const int*)d_in[1];
    float* out = (float*)d_out;

    const int T = 128;
    const int rows = in_sizes[1];              // V*C = 524288
    const long long cnt = (long long)rows * (T - 1);
    const float inv_cnt = 1.0f / (float)cnt;

    hipMemsetAsync(out, 0, sizeof(float), stream);

    // 2048 blocks: 8 blocks/CU co-resident (launch_bounds 256,8), 16384
    // half-wave slots, 8 chunk-iterations of 4 rows each.
    const int blocks = 2048;
    margin_loss_kernel<<<blocks, 256, 0, stream>>>(x, target, out, rows, inv_cnt);
}